// Round 1
// 234.498 us; speedup vs baseline: 1.0291x; 1.0291x over previous
//
#include <hip/hip_runtime.h>

typedef __bf16 bf16_t;
typedef __bf16 bf16x8 __attribute__((ext_vector_type(8)));
typedef __bf16 bf16x4 __attribute__((ext_vector_type(4)));
typedef float  floatx4 __attribute__((ext_vector_type(4)));

__device__ __forceinline__ void gload_lds16(const bf16_t* g, bf16_t* l) {
    __builtin_amdgcn_global_load_lds(
        (const __attribute__((address_space(1))) void*)g,
        (__attribute__((address_space(3))) void*)l,
        16, 0, 0);
}

// ---------------------------------------------------------------------------
// 256x256 8-phase counted-vmcnt GEMM (C = A * B^T, NT, row-major, K-contig).
// 512 threads = 8 waves (2M x 4N), wave tile 128x64, BK=64, 16x16x32 MFMA.
// LDS: 2 dbuf x {A,B} x {k0,k1} regions of 16 KB each = 128 KiB (dynamic).
// Region death order per K-tile with phase order (kk0,mh0)(kk0,mh1)(kk1,mh0)
// (kk1,mh1) is: Bk0 (after ph1), Ak0 (ph2), Bk1 (ph3), Ak1 (ph4) -> exactly
// one region per phase is restageable; stage targets below follow that with
// 6-phase lookahead. vmcnt(6) at phases 4 & 8 ONLY (3 half-tiles in flight);
// each vmcnt sits before a barrier so the landing guarantee is collective.
// Swizzle: 64 B region rows, slot = chunk ^ ((row>>1)&3): ds_read_b128 frag
// reads hit 8 distinct bank-quads per 16-lane group (2-way = free). Applied
// as linear LDS dest + pre-swizzled per-lane GLOBAL source (rule 21).
// MODE 1: z=0,1 -> bf16 C (Q,K); z=2 -> transposed stores (V^T).
// MODE 2: bf16 C = exp(acc*scale); per-row sums via atomicAdd.
// ---------------------------------------------------------------------------
template <int MODE, typename OutT>
__global__ __launch_bounds__(512, 2) void gemm8p(
    const bf16_t* __restrict__ A, int lda, size_t batchA,
    const bf16_t* __restrict__ B, int ldb, size_t batchB,
    OutT* __restrict__ C, int ldc, size_t batchC,
    bf16_t* __restrict__ C2, int ldc2,
    float* __restrict__ rowsums, int batchR,
    int K, float scale)
{
    extern __shared__ __align__(16) bf16_t smem[];

    A += (size_t)blockIdx.z * batchA;
    B += (size_t)blockIdx.z * batchB;

    const int tid  = threadIdx.x;
    const int wid  = tid >> 6;
    const int lane = tid & 63;
    const int wr   = wid >> 2;   // 0..1  (M wave row)
    const int wc   = wid & 3;    // 0..3  (N wave col)
    const int lr   = lane & 15;

    const int bm = blockIdx.x * 256;
    const int bn = blockIdx.y * 256;

    const bf16_t* At = A + (size_t)bm * lda;
    const bf16_t* Bt = B + (size_t)bn * ldb;

    // --- staging: per-lane constants. One region = 256 rows x 32 k (16 KB).
    // Two gload_lds per thread: instr i covers rows (i*8+wid)*16 + lane/4,
    // slot lane&3; LDS write is linear (base + lane*16) == row*32 + slot*8.
    // Source chunk for slot s of row r is s ^ ((r>>1)&3) = s ^ ((lane>>3)&3).
    const int    c8 = (((lane & 3) ^ ((lane >> 3) & 3)) << 3);
    const size_t ga = (size_t)(wid * 16 + (lane >> 2)) * lda + c8;
    const size_t gb = (size_t)(wid * 16 + (lane >> 2)) * ldb + c8;
    bf16_t* lw = smem + (wid << 9);   // wave's 1 KB staging chunk base

    // --- fragment reads: row r, k-chunk q=lane>>4 lives at slot q^((lr>>1)&3)
    const int slotoff = (((lane >> 4) ^ ((lr >> 1) & 3)) << 3);

    const int NT = K >> 6;            // 64-deep K tiles (must be even)

    floatx4 acc[8][4] = {};
    bf16x8 af[4], bq[4];

// region index: (buf<<2)|reg, reg: 0=Ak0 1=Ak1 2=Bk0 3=Bk1 (8192 elems each)
#define STAGE(sbuf, sreg, tile) do {                                          \
    bf16_t* _l = lw + ((((sbuf) << 2) | (sreg)) << 13);                       \
    const size_t _k = (size_t)(tile) * 64 + ((sreg) & 1) * 32;                \
    if ((sreg) >= 2) {                                                        \
        gload_lds16(Bt + _k + gb, _l);                                        \
        gload_lds16(Bt + _k + gb + (size_t)128 * ldb, _l + 4096);             \
    } else {                                                                  \
        gload_lds16(At + _k + ga, _l);                                        \
        gload_lds16(At + _k + ga + (size_t)128 * lda, _l + 4096);             \
    }                                                                         \
} while (0)

#define LDA_FRAG(buf, kk, row)                                                \
    (*(const bf16x8*)&smem[((((buf) << 2) | (kk)) << 13) + ((row) << 5) + slotoff])
#define LDB_FRAG(buf, kk, row)                                                \
    (*(const bf16x8*)&smem[((((buf) << 2) | (2 + (kk))) << 13) + ((row) << 5) + slotoff])

// One phase: ds-reads for THIS phase's MFMA quadrant, one half-tile stage,
// optional vmcnt(6), barrier, 16 MFMA under setprio(1), barrier.
#define PHASE(buf, kk, mh, RDB, sbuf, sreg, stile, DOVM) do {                 \
    if (RDB) {                                                                \
        _Pragma("unroll")                                                     \
        for (int j = 0; j < 4; ++j)                                           \
            bq[j] = LDB_FRAG(buf, kk, wc * 64 + j * 16 + lr);                 \
    }                                                                         \
    _Pragma("unroll")                                                         \
    for (int i = 0; i < 4; ++i)                                               \
        af[i] = LDA_FRAG(buf, kk, wr * 128 + (mh) * 64 + i * 16 + lr);        \
    STAGE(sbuf, sreg, stile);                                                 \
    if (DOVM) asm volatile("s_waitcnt vmcnt(6)" ::: "memory");                \
    __builtin_amdgcn_s_barrier();                                             \
    __builtin_amdgcn_s_setprio(1);                                            \
    _Pragma("unroll")                                                         \
    for (int i = 0; i < 4; ++i) {                                             \
        _Pragma("unroll")                                                     \
        for (int j = 0; j < 4; ++j)                                           \
            acc[(mh) * 4 + i][j] = __builtin_amdgcn_mfma_f32_16x16x32_bf16(   \
                bq[j], af[i], acc[(mh) * 4 + i][j], 0, 0, 0);                 \
    }                                                                         \
    __builtin_amdgcn_s_setprio(0);                                            \
    __builtin_amdgcn_s_barrier();                                             \
} while (0)

    // Prologue: tile0 fully + tile1's first 3 regions; vmcnt(6) leaves
    // exactly tile1's {Bk0,Ak0,Bk1} outstanding (= steady state at ph1).
    STAGE(0, 2, 0); STAGE(0, 0, 0); STAGE(0, 3, 0); STAGE(0, 1, 0);
    STAGE(1, 2, 1); STAGE(1, 0, 1); STAGE(1, 3, 1);
    asm volatile("s_waitcnt vmcnt(6)" ::: "memory");
    __builtin_amdgcn_s_barrier();

    for (int kt = 0; kt < NT; kt += 2) {
        int t1 = kt + 1;
        int t2 = kt + 2; if (t2 >= NT) t2 -= NT;   // tail wrap: harmless
        int t3 = kt + 3; if (t3 >= NT) t3 -= NT;   // redundant stage
        PHASE(0, 0, 0, true,  1, 1, t1, false);    // ph1  stage buf1.Ak1(t1)
        PHASE(0, 0, 1, false, 0, 2, t2, false);    // ph2  stage buf0.Bk0(t2)
        PHASE(0, 1, 0, true,  0, 0, t2, false);    // ph3  stage buf0.Ak0(t2)
        PHASE(0, 1, 1, false, 0, 3, t2, true);     // ph4  stage buf0.Bk1(t2) +vmcnt(6)
        PHASE(1, 0, 0, true,  0, 1, t2, false);    // ph5  stage buf0.Ak1(t2)
        PHASE(1, 0, 1, false, 1, 2, t3, false);    // ph6  stage buf1.Bk0(t3)
        PHASE(1, 1, 0, true,  1, 0, t3, false);    // ph7  stage buf1.Ak0(t3)
        PHASE(1, 1, 1, false, 1, 3, t3, true);     // ph8  stage buf1.Bk1(t3) +vmcnt(6)
    }
    asm volatile("s_waitcnt vmcnt(0)" ::: "memory");  // drain leftover stages

#undef PHASE
#undef LDA_FRAG
#undef LDB_FRAG
#undef STAGE

    // D layout: m = lane&15 (arg1 = af), n = (lane>>4)*4 + reg (arg0 = bq)
    const int cfix = lane & 15;
    const int creg = (lane >> 4) << 2;

    if constexpr (MODE == 1) {
        if (blockIdx.z == 2) {
            #pragma unroll
            for (int mi = 0; mi < 8; ++mi) {
                int mg = bm + wr * 128 + mi * 16 + cfix;
                #pragma unroll
                for (int j = 0; j < 4; ++j) {
                    int ng = bn + wc * 64 + j * 16 + creg;
                    #pragma unroll
                    for (int r = 0; r < 4; ++r)
                        C2[(size_t)(ng + r) * ldc2 + mg] = (bf16_t)acc[mi][j][r];
                }
            }
            return;
        }
        OutT* Cz = C + (size_t)blockIdx.z * batchC;
        #pragma unroll
        for (int mi = 0; mi < 8; ++mi) {
            size_t row = (size_t)(bm + wr * 128 + mi * 16 + cfix);
            #pragma unroll
            for (int j = 0; j < 4; ++j) {
                int col = bn + wc * 64 + j * 16 + creg;
                bf16x4 v;
                #pragma unroll
                for (int r = 0; r < 4; ++r) v[r] = (bf16_t)acc[mi][j][r];
                *(bf16x4*)&Cz[row * (size_t)ldc + col] = v;
            }
        }
    } else {  // MODE == 2
        OutT* Cz = C + (size_t)blockIdx.z * batchC;
        float* sums = rowsums + (size_t)blockIdx.z * batchR;
        float rs[8] = {};
        #pragma unroll
        for (int mi = 0; mi < 8; ++mi) {
            size_t row = (size_t)(bm + wr * 128 + mi * 16 + cfix);
            #pragma unroll
            for (int j = 0; j < 4; ++j) {
                int col = bn + wc * 64 + j * 16 + creg;
                bf16x4 v;
                #pragma unroll
                for (int r = 0; r < 4; ++r) {
                    v[r] = (bf16_t)__expf(acc[mi][j][r] * scale);
                    rs[mi] += (float)v[r];
                }
                *(bf16x4*)&Cz[row * (size_t)ldc + col] = v;
            }
        }
        #pragma unroll
        for (int mi = 0; mi < 8; ++mi) {
            rs[mi] += __shfl_xor(rs[mi], 16);
            rs[mi] += __shfl_xor(rs[mi], 32);
        }
        if (lane < 16) {
            #pragma unroll
            for (int mi = 0; mi < 8; ++mi)
                atomicAdd(&sums[bm + wr * 128 + mi * 16 + lane], rs[mi]);
        }
    }
}

// ---------------------------------------------------------------------------
// Legacy 128x128 kernel, retained for MODE 3 (PV): its 512-block grid fits
// residency exactly; a 256^2 8-phase PV would be only 128 blocks (50% util).
// ---------------------------------------------------------------------------
template <int MODE, int BKT, typename OutT>
__global__ __launch_bounds__(256) void gemm_nt(
    const bf16_t* __restrict__ A, int lda, size_t batchA,
    const bf16_t* __restrict__ B, int ldb, size_t batchB,
    OutT* __restrict__ C, int ldc, size_t batchC,
    bf16_t* __restrict__ C2, int ldc2,
    float* __restrict__ rowsums, int batchR,
    int K, float scale)
{
    constexpr int CH  = BKT / 8;
    constexpr int RPS = 2048 / BKT;
    constexpr int NSHOT = 128 / RPS;

    __shared__ bf16_t sA[128 * BKT];
    __shared__ bf16_t sB[128 * BKT];

    A += (size_t)blockIdx.z * batchA;
    B += (size_t)blockIdx.z * batchB;

    const int tid  = threadIdx.x;
    const int wid  = tid >> 6;
    const int lane = tid & 63;

    const int bm = blockIdx.x * 128;
    const int bn = blockIdx.y * 128;

    const int rr  = tid / CH;
    const int kc8 = (((tid & (CH - 1)) ^ (rr & (CH - 1))) << 3);

    const int wy = (wid >> 1) * 64;
    const int wx = (wid & 1) * 64;
    const int lr = lane & 15;

    floatx4 acc[4][4] = {};

    const bf16_t* pa = A + (size_t)(bm + rr) * lda + kc8;
    const bf16_t* pb = B + (size_t)(bn + rr) * ldb + kc8;
    bf16_t* la = &sA[wid * 512];
    bf16_t* lb = &sB[wid * 512];

    for (int k0 = 0; k0 < K; k0 += BKT) {
        #pragma unroll
        for (int c = 0; c < NSHOT; ++c) {
            gload_lds16(pa + (size_t)(c * RPS) * lda + k0, la + c * 2048);
            gload_lds16(pb + (size_t)(c * RPS) * ldb + k0, lb + c * 2048);
        }
        __syncthreads();

        #pragma unroll
        for (int kk = 0; kk < BKT / 32; ++kk) {
            const int cch = (kk << 2) + (lane >> 4);
            bf16x8 af[4], bqf[4];
            #pragma unroll
            for (int i = 0; i < 4; ++i) {
                int r = wy + i * 16 + lr;
                af[i] = *(const bf16x8*)&sA[r * BKT + ((cch ^ (r & (CH - 1))) << 3)];
            }
            #pragma unroll
            for (int j = 0; j < 4; ++j) {
                int r = wx + j * 16 + lr;
                bqf[j] = *(const bf16x8*)&sB[r * BKT + ((cch ^ (r & (CH - 1))) << 3)];
            }
            #pragma unroll
            for (int i = 0; i < 4; ++i)
                #pragma unroll
                for (int j = 0; j < 4; ++j)
                    acc[i][j] = __builtin_amdgcn_mfma_f32_16x16x32_bf16(
                        bqf[j], af[i], acc[i][j], 0, 0, 0);
        }
        __syncthreads();
    }

    const int cfix = lane & 15;
    const int creg = (lane >> 4) << 2;

    if constexpr (MODE == 3) {
        OutT* Cz = C + (size_t)blockIdx.z * batchC;
        const float* sums = rowsums + (size_t)blockIdx.z * batchR;
        #pragma unroll
        for (int i = 0; i < 4; ++i) {
            int rloc = bm + wy + i * 16 + cfix;
            float rinv = 1.0f / sums[rloc];
            size_t row = (size_t)rloc;
            #pragma unroll
            for (int j = 0; j < 4; ++j) {
                int col = bn + wx + j * 16 + creg;
                floatx4 v;
                #pragma unroll
                for (int r = 0; r < 4; ++r) v[r] = acc[i][j][r] * rinv;
                *(floatx4*)&Cz[row * (size_t)ldc + col] = v;
            }
        }
    }
    (void)C2; (void)ldc2; (void)scale;
}

// fused fp32->bf16 conversion over X, Wq, Wk, Wv + zeroing of rowsums
__global__ __launch_bounds__(256) void cvt_all(
    const float* __restrict__ X, const float* __restrict__ Wq,
    const float* __restrict__ Wk, const float* __restrict__ Wv,
    bf16_t* __restrict__ Xb, bf16_t* __restrict__ Wqb,
    bf16_t* __restrict__ Wkb, bf16_t* __restrict__ Wvb,
    float* __restrict__ sums, int nsums,
    int nX4, int nW4)
{
    int i = blockIdx.x * blockDim.x + threadIdx.x;
    if (i < nsums) sums[i] = 0.f;    // d_ws is re-poisoned before every call
    const float* src; bf16_t* dst; int idx;
    if (i < nX4) { src = X; dst = Xb; idx = i; }
    else {
        int j = i - nX4;
        int w = j / nW4;
        idx = j - w * nW4;
        if (i >= nX4 + 3 * nW4) return;
        src = (w == 0) ? Wq : (w == 1) ? Wk : Wv;
        dst = (w == 0) ? Wqb : (w == 1) ? Wkb : Wvb;
    }
    float4 v = ((const float4*)src)[idx];
    bf16x4 o;
    o[0] = (bf16_t)v.x; o[1] = (bf16_t)v.y; o[2] = (bf16_t)v.z; o[3] = (bf16_t)v.w;
    *(bf16x4*)(dst + (size_t)idx * 4) = o;
}

extern "C" void kernel_launch(void* const* d_in, const int* in_sizes, int n_in,
                              void* d_out, int out_size, void* d_ws, size_t ws_size,
                              hipStream_t stream)
{
    (void)in_sizes; (void)n_in; (void)out_size; (void)ws_size;
    const float* X  = (const float*)d_in[0];
    const float* Wq = (const float*)d_in[1];
    const float* Wk = (const float*)d_in[2];
    const float* Wv = (const float*)d_in[3];
    float* out = (float*)d_out;

    const int Bb = 4, S = 2048, D = 1024;
    const int M = Bb * S;  // 8192

    char* ws = (char*)d_ws;
    size_t off = 0;
    auto carve = [&](size_t bytes) -> char* {
        char* p = ws + off;
        off += (bytes + 255) & ~(size_t)255;
        return p;
    };
    // Contiguity invariants: Wqb,Wkb,Wvb adjacent (stride D*D);
    // Qb,Kb adjacent (stride M*D).
    bf16_t* Xb  = (bf16_t*)carve((size_t)M * D * 2);
    bf16_t* Wqb = (bf16_t*)carve((size_t)D * D * 2);
    bf16_t* Wkb = (bf16_t*)carve((size_t)D * D * 2);
    bf16_t* Wvb = (bf16_t*)carve((size_t)D * D * 2);
    bf16_t* Qb  = (bf16_t*)carve((size_t)M * D * 2);
    bf16_t* Kb  = (bf16_t*)carve((size_t)M * D * 2);
    bf16_t* Vt  = (bf16_t*)carve((size_t)D * M * 2);   // V^T: D x M
    bf16_t* Sc  = (bf16_t*)carve((size_t)Bb * S * S * 2);
    float*  sums = (float*)carve((size_t)M * 4);

    // 128 KiB dynamic LDS needs the opt-in attribute (host-side, capture-safe)
    static bool s_attr = false;
    if (!s_attr) {
        (void)hipFuncSetAttribute(
            reinterpret_cast<const void*>(&gemm8p<1, bf16_t>),
            hipFuncAttributeMaxDynamicSharedMemorySize, 131072);
        (void)hipFuncSetAttribute(
            reinterpret_cast<const void*>(&gemm8p<2, bf16_t>),
            hipFuncAttributeMaxDynamicSharedMemorySize, 131072);
        s_attr = true;
    }

    const int nX4 = M * D / 4, nW4 = D * D / 4;
    const int tot4 = nX4 + 3 * nW4;
    cvt_all<<<(tot4 + 255) / 256, 256, 0, stream>>>(
        X, Wq, Wk, Wv, Xb, Wqb, Wkb, Wvb, sums, M, nX4, nW4);

    // z=0: Q = X Wq^T ; z=1: K = X Wk^T ; z=2: V^T = (X Wv^T)^T
    gemm8p<1, bf16_t><<<dim3(M / 256, D / 256, 3), 512, 131072, stream>>>(
        Xb, D, 0, Wqb, D, (size_t)D * D, Qb, D, (size_t)M * D,
        Vt, M, nullptr, 0, D, 1.0f);

    // Sc = exp(Q K^T / 32) + row sums.
    gemm8p<2, bf16_t><<<dim3(S / 256, S / 256, Bb), 512, 131072, stream>>>(
        Qb, D, (size_t)S * D, Kb, D, (size_t)S * D, Sc, S, (size_t)S * S,
        nullptr, 0, sums, S, D, 0.03125f);

    // out = (Sc V) / rowsum  (legacy 128^2 kernel, BK=128)
    gemm_nt<3, 128, float><<<dim3(S / 128, D / 128, Bb), 256, 0, stream>>>(
        Sc, S, (size_t)S * S, Vt, M, (size_t)S, out, D, (size_t)S * D,
        nullptr, 0, sums, S, S, 1.0f);
}

// Round 2
// 234.396 us; speedup vs baseline: 1.0295x; 1.0004x over previous
//
#include <hip/hip_runtime.h>

typedef __bf16 bf16_t;
typedef __bf16 bf16x8 __attribute__((ext_vector_type(8)));
typedef __bf16 bf16x4 __attribute__((ext_vector_type(4)));
typedef float  floatx4 __attribute__((ext_vector_type(4)));

__device__ __forceinline__ void gload_lds16(const bf16_t* g, bf16_t* l) {
    __builtin_amdgcn_global_load_lds(
        (const __attribute__((address_space(1))) void*)g,
        (__attribute__((address_space(3))) void*)l,
        16, 0, 0);
}

// ---------------------------------------------------------------------------
// 256x256 8-phase counted-vmcnt GEMM (C = A * B^T, NT, row-major, K-contig).
// 512 threads = 8 waves (2M x 4N), wave tile 128x64, BK=64, 16x16x32 MFMA.
// LDS 128 KiB + ~250 regs/wave => exactly 1 block/CU. THEREFORE: grids must
// be <= 256 blocks per pass (round-1 lesson: 384 blocks = 2 ragged passes,
// -25%). Launchers below keep every gemm8p grid at exactly 256 blocks.
// vmcnt(6) at phases 4 & 8 only; 2 raw barriers/phase; setprio around MFMA.
// MODE 1: bf16 C store (used for fused QK: C is [M][2048], Q||K halves).
// MODE 2: bf16 C = exp(acc*scale); per-row sums via atomicAdd.
// ---------------------------------------------------------------------------
template <int MODE, typename OutT>
__global__ __launch_bounds__(512, 2) void gemm8p(
    const bf16_t* __restrict__ A, int lda, size_t batchA,
    const bf16_t* __restrict__ B, int ldb, size_t batchB,
    OutT* __restrict__ C, int ldc, size_t batchC,
    float* __restrict__ rowsums, int batchR,
    int K, float scale)
{
    extern __shared__ __align__(16) bf16_t smem[];

    A += (size_t)blockIdx.z * batchA;
    B += (size_t)blockIdx.z * batchB;

    const int tid  = threadIdx.x;
    const int wid  = tid >> 6;
    const int lane = tid & 63;
    const int wr   = wid >> 2;   // 0..1  (M wave row)
    const int wc   = wid & 3;    // 0..3  (N wave col)
    const int lr   = lane & 15;

    const int bm = blockIdx.x * 256;
    const int bn = blockIdx.y * 256;

    const bf16_t* At = A + (size_t)bm * lda;
    const bf16_t* Bt = B + (size_t)bn * ldb;

    // staging constants: one region = 256 rows x 32 k (16 KB), 2 gloads/thr.
    // LDS dest linear; source chunk pre-swizzled: slot s of row r holds
    // chunk s ^ ((r>>1)&3).
    const int    c8 = (((lane & 3) ^ ((lane >> 3) & 3)) << 3);
    const size_t ga = (size_t)(wid * 16 + (lane >> 2)) * lda + c8;
    const size_t gb = (size_t)(wid * 16 + (lane >> 2)) * ldb + c8;
    bf16_t* lw = smem + (wid << 9);

    // fragment reads: row r, k-chunk q=lane>>4 lives at slot q^((lr>>1)&3)
    const int slotoff = (((lane >> 4) ^ ((lr >> 1) & 3)) << 3);

    const int NT = K >> 6;            // 64-deep K tiles (even)

    floatx4 acc[8][4] = {};
    bf16x8 af[4], bq[4];

#define STAGE(sbuf, sreg, tile) do {                                          \
    bf16_t* _l = lw + ((((sbuf) << 2) | (sreg)) << 13);                       \
    const size_t _k = (size_t)(tile) * 64 + ((sreg) & 1) * 32;                \
    if ((sreg) >= 2) {                                                        \
        gload_lds16(Bt + _k + gb, _l);                                        \
        gload_lds16(Bt + _k + gb + (size_t)128 * ldb, _l + 4096);             \
    } else {                                                                  \
        gload_lds16(At + _k + ga, _l);                                        \
        gload_lds16(At + _k + ga + (size_t)128 * lda, _l + 4096);             \
    }                                                                         \
} while (0)

#define LDA_FRAG(buf, kk, row)                                                \
    (*(const bf16x8*)&smem[((((buf) << 2) | (kk)) << 13) + ((row) << 5) + slotoff])
#define LDB_FRAG(buf, kk, row)                                                \
    (*(const bf16x8*)&smem[((((buf) << 2) | (2 + (kk))) << 13) + ((row) << 5) + slotoff])

#define PHASE(buf, kk, mh, RDB, sbuf, sreg, stile, DOVM) do {                 \
    if (RDB) {                                                                \
        _Pragma("unroll")                                                     \
        for (int j = 0; j < 4; ++j)                                           \
            bq[j] = LDB_FRAG(buf, kk, wc * 64 + j * 16 + lr);                 \
    }                                                                         \
    _Pragma("unroll")                                                         \
    for (int i = 0; i < 4; ++i)                                               \
        af[i] = LDA_FRAG(buf, kk, wr * 128 + (mh) * 64 + i * 16 + lr);        \
    STAGE(sbuf, sreg, stile);                                                 \
    if (DOVM) asm volatile("s_waitcnt vmcnt(6)" ::: "memory");                \
    __builtin_amdgcn_s_barrier();                                             \
    __builtin_amdgcn_s_setprio(1);                                            \
    _Pragma("unroll")                                                         \
    for (int i = 0; i < 4; ++i) {                                             \
        _Pragma("unroll")                                                     \
        for (int j = 0; j < 4; ++j)                                           \
            acc[(mh) * 4 + i][j] = __builtin_amdgcn_mfma_f32_16x16x32_bf16(   \
                bq[j], af[i], acc[(mh) * 4 + i][j], 0, 0, 0);                 \
    }                                                                         \
    __builtin_amdgcn_s_setprio(0);                                            \
    __builtin_amdgcn_s_barrier();                                             \
} while (0)

    STAGE(0, 2, 0); STAGE(0, 0, 0); STAGE(0, 3, 0); STAGE(0, 1, 0);
    STAGE(1, 2, 1); STAGE(1, 0, 1); STAGE(1, 3, 1);
    asm volatile("s_waitcnt vmcnt(6)" ::: "memory");
    __builtin_amdgcn_s_barrier();

    for (int kt = 0; kt < NT; kt += 2) {
        int t1 = kt + 1;
        int t2 = kt + 2; if (t2 >= NT) t2 -= NT;
        int t3 = kt + 3; if (t3 >= NT) t3 -= NT;
        PHASE(0, 0, 0, true,  1, 1, t1, false);
        PHASE(0, 0, 1, false, 0, 2, t2, false);
        PHASE(0, 1, 0, true,  0, 0, t2, false);
        PHASE(0, 1, 1, false, 0, 3, t2, true);
        PHASE(1, 0, 0, true,  0, 1, t2, false);
        PHASE(1, 0, 1, false, 1, 2, t3, false);
        PHASE(1, 1, 0, true,  1, 0, t3, false);
        PHASE(1, 1, 1, false, 1, 3, t3, true);
    }
    asm volatile("s_waitcnt vmcnt(0)" ::: "memory");

#undef PHASE
#undef LDA_FRAG
#undef LDB_FRAG
#undef STAGE

    // D layout: m = lane&15 (arg1 = af), n = (lane>>4)*4 + reg (arg0 = bq)
    const int cfix = lane & 15;
    const int creg = (lane >> 4) << 2;

    if constexpr (MODE == 1) {
        OutT* Cz = C + (size_t)blockIdx.z * batchC;
        #pragma unroll
        for (int mi = 0; mi < 8; ++mi) {
            size_t row = (size_t)(bm + wr * 128 + mi * 16 + cfix);
            #pragma unroll
            for (int j = 0; j < 4; ++j) {
                int col = bn + wc * 64 + j * 16 + creg;
                bf16x4 v;
                #pragma unroll
                for (int r = 0; r < 4; ++r) v[r] = (bf16_t)acc[mi][j][r];
                *(bf16x4*)&Cz[row * (size_t)ldc + col] = v;
            }
        }
    } else {  // MODE == 2
        OutT* Cz = C + (size_t)blockIdx.z * batchC;
        float* sums = rowsums + (size_t)blockIdx.z * batchR;
        float rs[8] = {};
        #pragma unroll
        for (int mi = 0; mi < 8; ++mi) {
            size_t row = (size_t)(bm + wr * 128 + mi * 16 + cfix);
            #pragma unroll
            for (int j = 0; j < 4; ++j) {
                int col = bn + wc * 64 + j * 16 + creg;
                bf16x4 v;
                #pragma unroll
                for (int r = 0; r < 4; ++r) {
                    v[r] = (bf16_t)__expf(acc[mi][j][r] * scale);
                    rs[mi] += (float)v[r];
                }
                *(bf16x4*)&Cz[row * (size_t)ldc + col] = v;
            }
        }
        #pragma unroll
        for (int mi = 0; mi < 8; ++mi) {
            rs[mi] += __shfl_xor(rs[mi], 16);
            rs[mi] += __shfl_xor(rs[mi], 32);
        }
        if (lane < 16) {
            #pragma unroll
            for (int mi = 0; mi < 8; ++mi)
                atomicAdd(&sums[bm + wr * 128 + mi * 16 + lane], rs[mi]);
        }
    }
}

// ---------------------------------------------------------------------------
// Legacy 128x128 kernel (2-barrier loop). 2 blocks/CU residency -> best for
// grids > 256 blocks. MODE 3: PV with normalization (C float).
// MODE 4: V^T (transpose store to C2), z ignored.
// ---------------------------------------------------------------------------
template <int MODE, int BKT, typename OutT>
__global__ __launch_bounds__(256) void gemm_nt(
    const bf16_t* __restrict__ A, int lda, size_t batchA,
    const bf16_t* __restrict__ B, int ldb, size_t batchB,
    OutT* __restrict__ C, int ldc, size_t batchC,
    bf16_t* __restrict__ C2, int ldc2,
    float* __restrict__ rowsums, int batchR,
    int K, float scale)
{
    constexpr int CH  = BKT / 8;
    constexpr int RPS = 2048 / BKT;
    constexpr int NSHOT = 128 / RPS;

    __shared__ bf16_t sA[128 * BKT];
    __shared__ bf16_t sB[128 * BKT];

    A += (size_t)blockIdx.z * batchA;
    B += (size_t)blockIdx.z * batchB;

    const int tid  = threadIdx.x;
    const int wid  = tid >> 6;
    const int lane = tid & 63;

    const int bm = blockIdx.x * 128;
    const int bn = blockIdx.y * 128;

    const int rr  = tid / CH;
    const int kc8 = (((tid & (CH - 1)) ^ (rr & (CH - 1))) << 3);

    const int wy = (wid >> 1) * 64;
    const int wx = (wid & 1) * 64;
    const int lr = lane & 15;

    floatx4 acc[4][4] = {};

    const bf16_t* pa = A + (size_t)(bm + rr) * lda + kc8;
    const bf16_t* pb = B + (size_t)(bn + rr) * ldb + kc8;
    bf16_t* la = &sA[wid * 512];
    bf16_t* lb = &sB[wid * 512];

    for (int k0 = 0; k0 < K; k0 += BKT) {
        #pragma unroll
        for (int c = 0; c < NSHOT; ++c) {
            gload_lds16(pa + (size_t)(c * RPS) * lda + k0, la + c * 2048);
            gload_lds16(pb + (size_t)(c * RPS) * ldb + k0, lb + c * 2048);
        }
        __syncthreads();

        #pragma unroll
        for (int kk = 0; kk < BKT / 32; ++kk) {
            const int cch = (kk << 2) + (lane >> 4);
            bf16x8 af[4], bqf[4];
            #pragma unroll
            for (int i = 0; i < 4; ++i) {
                int r = wy + i * 16 + lr;
                af[i] = *(const bf16x8*)&sA[r * BKT + ((cch ^ (r & (CH - 1))) << 3)];
            }
            #pragma unroll
            for (int j = 0; j < 4; ++j) {
                int r = wx + j * 16 + lr;
                bqf[j] = *(const bf16x8*)&sB[r * BKT + ((cch ^ (r & (CH - 1))) << 3)];
            }
            #pragma unroll
            for (int i = 0; i < 4; ++i)
                #pragma unroll
                for (int j = 0; j < 4; ++j)
                    acc[i][j] = __builtin_amdgcn_mfma_f32_16x16x32_bf16(
                        bqf[j], af[i], acc[i][j], 0, 0, 0);
        }
        __syncthreads();
    }

    const int cfix = lane & 15;
    const int creg = (lane >> 4) << 2;

    if constexpr (MODE == 3) {
        OutT* Cz = C + (size_t)blockIdx.z * batchC;
        const float* sums = rowsums + (size_t)blockIdx.z * batchR;
        #pragma unroll
        for (int i = 0; i < 4; ++i) {
            int rloc = bm + wy + i * 16 + cfix;
            float rinv = 1.0f / sums[rloc];
            size_t row = (size_t)rloc;
            #pragma unroll
            for (int j = 0; j < 4; ++j) {
                int col = bn + wx + j * 16 + creg;
                floatx4 v;
                #pragma unroll
                for (int r = 0; r < 4; ++r) v[r] = acc[i][j][r] * rinv;
                *(floatx4*)&Cz[row * (size_t)ldc + col] = v;
            }
        }
    } else if constexpr (MODE == 4) {
        // V^T: C2[d][s] = acc, d = n-coord, s = m-coord
        #pragma unroll
        for (int i = 0; i < 4; ++i) {
            int mg = bm + wy + i * 16 + cfix;
            #pragma unroll
            for (int j = 0; j < 4; ++j) {
                int ng = bn + wx + j * 16 + creg;
                #pragma unroll
                for (int r = 0; r < 4; ++r)
                    C2[(size_t)(ng + r) * ldc2 + mg] = (bf16_t)acc[i][j][r];
            }
        }
    }
    (void)C; (void)ldc; (void)batchC; (void)C2; (void)ldc2;
    (void)rowsums; (void)batchR; (void)scale;
}

// fused fp32->bf16 conversion over X, Wq, Wk, Wv + zeroing of rowsums
__global__ __launch_bounds__(256) void cvt_all(
    const float* __restrict__ X, const float* __restrict__ Wq,
    const float* __restrict__ Wk, const float* __restrict__ Wv,
    bf16_t* __restrict__ Xb, bf16_t* __restrict__ Wqb,
    bf16_t* __restrict__ Wkb, bf16_t* __restrict__ Wvb,
    float* __restrict__ sums, int nsums,
    int nX4, int nW4)
{
    int i = blockIdx.x * blockDim.x + threadIdx.x;
    if (i < nsums) sums[i] = 0.f;    // d_ws is re-poisoned before every call
    const float* src; bf16_t* dst; int idx;
    if (i < nX4) { src = X; dst = Xb; idx = i; }
    else {
        int j = i - nX4;
        int w = j / nW4;
        idx = j - w * nW4;
        if (i >= nX4 + 3 * nW4) return;
        src = (w == 0) ? Wq : (w == 1) ? Wk : Wv;
        dst = (w == 0) ? Wqb : (w == 1) ? Wkb : Wvb;
    }
    float4 v = ((const float4*)src)[idx];
    bf16x4 o;
    o[0] = (bf16_t)v.x; o[1] = (bf16_t)v.y; o[2] = (bf16_t)v.z; o[3] = (bf16_t)v.w;
    *(bf16x4*)(dst + (size_t)idx * 4) = o;
}

extern "C" void kernel_launch(void* const* d_in, const int* in_sizes, int n_in,
                              void* d_out, int out_size, void* d_ws, size_t ws_size,
                              hipStream_t stream)
{
    (void)in_sizes; (void)n_in; (void)out_size; (void)ws_size;
    const float* X  = (const float*)d_in[0];
    const float* Wq = (const float*)d_in[1];
    const float* Wk = (const float*)d_in[2];
    const float* Wv = (const float*)d_in[3];
    float* out = (float*)d_out;

    const int Bb = 4, S = 2048, D = 1024;
    const int M = Bb * S;  // 8192

    char* ws = (char*)d_ws;
    size_t off = 0;
    auto carve = [&](size_t bytes) -> char* {
        char* p = ws + off;
        off += (bytes + 255) & ~(size_t)255;
        return p;
    };
    // Contiguity invariants: Wqb,Wkb adjacent (2 MB each, 256-aligned ->
    // Wkb == Wqb + D*D exactly): fused-QK B-matrix is Wqb as [2048][1024].
    bf16_t* Xb  = (bf16_t*)carve((size_t)M * D * 2);
    bf16_t* Wqb = (bf16_t*)carve((size_t)D * D * 2);
    bf16_t* Wkb = (bf16_t*)carve((size_t)D * D * 2);
    bf16_t* Wvb = (bf16_t*)carve((size_t)D * D * 2);
    bf16_t* QKb = (bf16_t*)carve((size_t)M * 2 * D * 2);  // [M][2048]: Q||K
    bf16_t* Vt  = (bf16_t*)carve((size_t)D * M * 2);      // V^T: D x M
    bf16_t* Sc  = (bf16_t*)carve((size_t)Bb * S * S * 2);
    float*  sums = (float*)carve((size_t)M * 4);

    static bool s_attr = false;
    if (!s_attr) {
        (void)hipFuncSetAttribute(
            reinterpret_cast<const void*>(&gemm8p<1, bf16_t>),
            hipFuncAttributeMaxDynamicSharedMemorySize, 131072);
        (void)hipFuncSetAttribute(
            reinterpret_cast<const void*>(&gemm8p<2, bf16_t>),
            hipFuncAttributeMaxDynamicSharedMemorySize, 131072);
        s_attr = true;
    }

    const int nX4 = M * D / 4, nW4 = D * D / 4;
    const int tot4 = nX4 + 3 * nW4;
    cvt_all<<<(tot4 + 255) / 256, 256, 0, stream>>>(
        X, Wq, Wk, Wv, Xb, Wqb, Wkb, Wvb, sums, M, nX4, nW4);

    // Fused QK: C[M][2048] = X * (Wq||Wk)^T. Grid 32x8 = 256 blocks (1 pass).
    gemm8p<1, bf16_t><<<dim3(M / 256, (2 * D) / 256, 1), 512, 131072, stream>>>(
        Xb, D, 0, Wqb, D, 0, QKb, 2 * D, 0,
        nullptr, 0, D, 1.0f);

    // V^T = (X Wv^T)^T via legacy kernel: 512 blocks at 2/CU (1 pass).
    gemm_nt<4, 64, bf16_t><<<dim3(M / 128, D / 128, 1), 256, 0, stream>>>(
        Xb, D, 0, Wvb, D, 0, nullptr, 0, 0,
        Vt, M, nullptr, 0, D, 1.0f);

    // Sc = exp(Q K^T / 32) + row sums. Q = QKb[:,0:1024], K = QKb[:,1024:2048].
    // Grid 8x8x4 = 256 blocks (1 pass).
    gemm8p<2, bf16_t><<<dim3(S / 256, S / 256, Bb), 512, 131072, stream>>>(
        QKb, 2 * D, (size_t)S * 2 * D, QKb + D, 2 * D, (size_t)S * 2 * D,
        Sc, S, (size_t)S * S, sums, S, D, 0.03125f);

    // out = (Sc V) / rowsum  (legacy kernel, 512 blocks at 2/CU).
    gemm_nt<3, 128, float><<<dim3(S / 128, D / 128, Bb), 256, 0, stream>>>(
        Sc, S, (size_t)S * S, Vt, M, (size_t)S, out, D, (size_t)S * D,
        nullptr, 0, sums, S, S, 1.0f);
}

// Round 3
// 230.703 us; speedup vs baseline: 1.0460x; 1.0160x over previous
//
#include <hip/hip_runtime.h>

typedef __bf16 bf16_t;
typedef __bf16 bf16x8 __attribute__((ext_vector_type(8)));
typedef __bf16 bf16x4 __attribute__((ext_vector_type(4)));
typedef float  floatx4 __attribute__((ext_vector_type(4)));

__device__ __forceinline__ void gload_lds16(const bf16_t* g, bf16_t* l) {
    __builtin_amdgcn_global_load_lds(
        (const __attribute__((address_space(1))) void*)g,
        (__attribute__((address_space(3))) void*)l,
        16, 0, 0);
}

// ---------------------------------------------------------------------------
// 256xBN 8-phase counted-vmcnt GEMM (C = A * B^T, NT, row-major, K-contig).
// 512 threads = 8 waves (2M x 4N); wave tile 128 x (BN/4); BK=64.
// BN=256: LDS 128 KiB, regions all 16 KB (2 gloads/thr), vmcnt(6).
// BN=128: LDS  96 KiB, B regions 8 KB (1 gload/thr),     vmcnt(4).
//   vmcnt ledger (gload units): leave = newest {ph2,ph3,ph4} = 2+2*BGL.
//   Verified: ph1/ph3 reads covered by prev ph8's wait (lands through prev
//   ph5); ph5/ph7 reads covered by ph4's wait (lands through ph1).
// 1 block/CU in both shapes => grids must be exactly <=256 blocks (round-1
// lesson: 384 blocks = 2 ragged passes, -25%). All launches below are 256.
// MODE 1: plain bf16 C store                       (V^T direct, BN=128)
// MODE 2: bf16 C = exp(acc*scale) + atomic rowsums (Sc, BN=256)
// MODE 3: float C = acc / rowsums[row]             (PV, BN=128)
// MODE 5: split store: bn<1024 -> C (Q), else C2 (K), col = bn&1023 (BN=256)
// ---------------------------------------------------------------------------
template <int MODE, int BN, typename OutT>
__global__ __launch_bounds__(512, 2) void gemm8p(
    const bf16_t* __restrict__ A, int lda, size_t batchA,
    const bf16_t* __restrict__ B, int ldb, size_t batchB,
    OutT* __restrict__ C, int ldc, size_t batchC,
    bf16_t* __restrict__ C2,
    float* __restrict__ rowsums, int batchR,
    int K, float scale)
{
    extern __shared__ __align__(16) bf16_t smem[];

    constexpr int NJ   = BN / 64;        // B-fragments per wave (4 or 2)
    constexpr int WCB  = BN / 4;         // wave col base stride (64 or 32)
    constexpr int BGL  = BN / 128;       // gloads per B-region (2 or 1)
    constexpr int AREG = 8192;           // A region elems (256 rows x 32 k)
    constexpr int BREG = BN * 32;        // B region elems (BN rows x 32 k)
    constexpr int BOFF = 2 * AREG;
    constexpr int BUFS = BOFF + 2 * BREG;  // per-dbuf elems
    constexpr int VM   = 2 + 2 * BGL;    // counted vmcnt (6 or 4)

    A += (size_t)blockIdx.z * batchA;
    B += (size_t)blockIdx.z * batchB;

    const int tid  = threadIdx.x;
    const int wid  = tid >> 6;
    const int lane = tid & 63;
    const int wr   = wid >> 2;   // 0..1  (M wave row)
    const int wc   = wid & 3;    // 0..3  (N wave col)
    const int lr   = lane & 15;

    const int bm = blockIdx.x * 256;
    const int bn = blockIdx.y * BN;

    const bf16_t* At = A + (size_t)bm * lda;
    const bf16_t* Bt = B + (size_t)bn * ldb;

    // staging: region rows are 64 B (4 x 16 B chunks); LDS dest linear,
    // source chunk pre-swizzled: slot s of row r holds chunk s^((r>>1)&3).
    const int    c8 = (((lane & 3) ^ ((lane >> 3) & 3)) << 3);
    const size_t ga = (size_t)(wid * 16 + (lane >> 2)) * lda + c8;
    const size_t gb = (size_t)(wid * 16 + (lane >> 2)) * ldb + c8;

    // fragment reads: row r, k-chunk q=lane>>4 lives at slot q^((lr>>1)&3)
    const int slotoff = (((lane >> 4) ^ ((lr >> 1) & 3)) << 3);

    const int NT = K >> 6;            // 64-deep K tiles (even)

    floatx4 acc[8][NJ] = {};
    bf16x8 af[4], bq[NJ];

#define RBASE(sbuf, sreg)                                                     \
    ((sbuf) * BUFS + ((sreg) < 2 ? (sreg) * AREG : BOFF + ((sreg) - 2) * BREG))

#define STAGE(sbuf, sreg, tile) do {                                          \
    bf16_t* _l = smem + RBASE(sbuf, sreg) + (wid << 9);                       \
    const size_t _k = (size_t)(tile) * 64 + ((sreg) & 1) * 32;                \
    if ((sreg) >= 2) {                                                        \
        gload_lds16(Bt + _k + gb, _l);                                        \
        if (BGL == 2)                                                         \
            gload_lds16(Bt + _k + gb + (size_t)128 * ldb, _l + 4096);         \
    } else {                                                                  \
        gload_lds16(At + _k + ga, _l);                                        \
        gload_lds16(At + _k + ga + (size_t)128 * lda, _l + 4096);             \
    }                                                                         \
} while (0)

#define LDA_FRAG(buf, kk, row)                                                \
    (*(const bf16x8*)&smem[(buf) * BUFS + (kk) * AREG + ((row) << 5) + slotoff])
#define LDB_FRAG(buf, kk, row)                                                \
    (*(const bf16x8*)&smem[(buf) * BUFS + BOFF + (kk) * BREG + ((row) << 5) + slotoff])

#define PHASE(buf, kk, mh, RDB, sbuf, sreg, stile, DOVM) do {                 \
    if (RDB) {                                                                \
        _Pragma("unroll")                                                     \
        for (int j = 0; j < NJ; ++j)                                          \
            bq[j] = LDB_FRAG(buf, kk, wc * WCB + j * 16 + lr);                \
    }                                                                         \
    _Pragma("unroll")                                                         \
    for (int i = 0; i < 4; ++i)                                               \
        af[i] = LDA_FRAG(buf, kk, wr * 128 + (mh) * 64 + i * 16 + lr);        \
    STAGE(sbuf, sreg, stile);                                                 \
    if (DOVM) {                                                               \
        if constexpr (VM == 6) asm volatile("s_waitcnt vmcnt(6)" ::: "memory");\
        else                   asm volatile("s_waitcnt vmcnt(4)" ::: "memory");\
    }                                                                         \
    __builtin_amdgcn_s_barrier();                                             \
    __builtin_amdgcn_s_setprio(1);                                            \
    _Pragma("unroll")                                                         \
    for (int i = 0; i < 4; ++i) {                                             \
        _Pragma("unroll")                                                     \
        for (int j = 0; j < NJ; ++j)                                          \
            acc[(mh) * 4 + i][j] = __builtin_amdgcn_mfma_f32_16x16x32_bf16(   \
                bq[j], af[i], acc[(mh) * 4 + i][j], 0, 0, 0);                 \
    }                                                                         \
    __builtin_amdgcn_s_setprio(0);                                            \
    __builtin_amdgcn_s_barrier();                                             \
} while (0)

    // Prologue: buf0 fully + buf1 {Bk0,Ak0,Bk1}; vmcnt(VM) leaves exactly
    // buf1's three regions outstanding => buf0 landed before ph1.
    STAGE(0, 2, 0); STAGE(0, 0, 0); STAGE(0, 3, 0); STAGE(0, 1, 0);
    STAGE(1, 2, 1); STAGE(1, 0, 1); STAGE(1, 3, 1);
    if constexpr (VM == 6) asm volatile("s_waitcnt vmcnt(6)" ::: "memory");
    else                   asm volatile("s_waitcnt vmcnt(4)" ::: "memory");
    __builtin_amdgcn_s_barrier();

    for (int kt = 0; kt < NT; kt += 2) {
        int t1 = kt + 1;
        int t2 = kt + 2; if (t2 >= NT) t2 -= NT;   // tail wrap: redundant
        int t3 = kt + 3; if (t3 >= NT) t3 -= NT;   // stages, harmless
        PHASE(0, 0, 0, true,  1, 1, t1, false);
        PHASE(0, 0, 1, false, 0, 2, t2, false);
        PHASE(0, 1, 0, true,  0, 0, t2, false);
        PHASE(0, 1, 1, false, 0, 3, t2, true);
        PHASE(1, 0, 0, true,  0, 1, t2, false);
        PHASE(1, 0, 1, false, 1, 2, t3, false);
        PHASE(1, 1, 0, true,  1, 0, t3, false);
        PHASE(1, 1, 1, false, 1, 3, t3, true);
    }
    asm volatile("s_waitcnt vmcnt(0)" ::: "memory");

#undef PHASE
#undef LDA_FRAG
#undef LDB_FRAG
#undef STAGE
#undef RBASE

    // D layout: m = lane&15 (arg1 = af), n = (lane>>4)*4 + reg (arg0 = bq)
    const int cfix = lane & 15;
    const int creg = (lane >> 4) << 2;

    if constexpr (MODE == 1) {
        OutT* Cz = C + (size_t)blockIdx.z * batchC;
        #pragma unroll
        for (int mi = 0; mi < 8; ++mi) {
            size_t row = (size_t)(bm + wr * 128 + mi * 16 + cfix);
            #pragma unroll
            for (int j = 0; j < NJ; ++j) {
                int col = bn + wc * WCB + j * 16 + creg;
                bf16x4 v;
                #pragma unroll
                for (int r = 0; r < 4; ++r) v[r] = (bf16_t)acc[mi][j][r];
                *(bf16x4*)&Cz[row * (size_t)ldc + col] = v;
            }
        }
    } else if constexpr (MODE == 5) {
        // fused QK split: cols [0,1024) -> C (Q), [1024,2048) -> C2 (K)
        bf16_t* dst = (bn < 1024) ? (bf16_t*)C : C2;
        const int cb = bn & 1023;
        #pragma unroll
        for (int mi = 0; mi < 8; ++mi) {
            size_t row = (size_t)(bm + wr * 128 + mi * 16 + cfix);
            #pragma unroll
            for (int j = 0; j < NJ; ++j) {
                int col = cb + wc * WCB + j * 16 + creg;
                bf16x4 v;
                #pragma unroll
                for (int r = 0; r < 4; ++r) v[r] = (bf16_t)acc[mi][j][r];
                *(bf16x4*)&dst[row * (size_t)ldc + col] = v;
            }
        }
    } else if constexpr (MODE == 2) {
        OutT* Cz = C + (size_t)blockIdx.z * batchC;
        float* sums = rowsums + (size_t)blockIdx.z * batchR;
        float rs[8] = {};
        #pragma unroll
        for (int mi = 0; mi < 8; ++mi) {
            size_t row = (size_t)(bm + wr * 128 + mi * 16 + cfix);
            #pragma unroll
            for (int j = 0; j < NJ; ++j) {
                int col = bn + wc * WCB + j * 16 + creg;
                bf16x4 v;
                #pragma unroll
                for (int r = 0; r < 4; ++r) {
                    v[r] = (bf16_t)__expf(acc[mi][j][r] * scale);
                    rs[mi] += (float)v[r];
                }
                *(bf16x4*)&Cz[row * (size_t)ldc + col] = v;
            }
        }
        #pragma unroll
        for (int mi = 0; mi < 8; ++mi) {
            rs[mi] += __shfl_xor(rs[mi], 16);
            rs[mi] += __shfl_xor(rs[mi], 32);
        }
        if (lane < 16) {
            #pragma unroll
            for (int mi = 0; mi < 8; ++mi)
                atomicAdd(&sums[bm + wr * 128 + mi * 16 + lane], rs[mi]);
        }
    } else {  // MODE == 3: PV with normalization
        OutT* Cz = C + (size_t)blockIdx.z * batchC;
        const float* sums = rowsums + (size_t)blockIdx.z * batchR;
        #pragma unroll
        for (int mi = 0; mi < 8; ++mi) {
            int rloc = bm + wr * 128 + mi * 16 + cfix;
            float rinv = 1.0f / sums[rloc];
            size_t row = (size_t)rloc;
            #pragma unroll
            for (int j = 0; j < NJ; ++j) {
                int col = bn + wc * WCB + j * 16 + creg;
                floatx4 v;
                #pragma unroll
                for (int r = 0; r < 4; ++r) v[r] = acc[mi][j][r] * rinv;
                *(floatx4*)&Cz[row * (size_t)ldc + col] = v;
            }
        }
    }
}

// fused fp32->bf16 conversion over X, Wq, Wk, Wv + zeroing of rowsums
__global__ __launch_bounds__(256) void cvt_all(
    const float* __restrict__ X, const float* __restrict__ Wq,
    const float* __restrict__ Wk, const float* __restrict__ Wv,
    bf16_t* __restrict__ Xb, bf16_t* __restrict__ Wqb,
    bf16_t* __restrict__ Wkb, bf16_t* __restrict__ Wvb,
    float* __restrict__ sums, int nsums,
    int nX4, int nW4)
{
    int i = blockIdx.x * blockDim.x + threadIdx.x;
    if (i < nsums) sums[i] = 0.f;    // d_ws is re-poisoned before every call
    const float* src; bf16_t* dst; int idx;
    if (i < nX4) { src = X; dst = Xb; idx = i; }
    else {
        int j = i - nX4;
        int w = j / nW4;
        idx = j - w * nW4;
        if (i >= nX4 + 3 * nW4) return;
        src = (w == 0) ? Wq : (w == 1) ? Wk : Wv;
        dst = (w == 0) ? Wqb : (w == 1) ? Wkb : Wvb;
    }
    float4 v = ((const float4*)src)[idx];
    bf16x4 o;
    o[0] = (bf16_t)v.x; o[1] = (bf16_t)v.y; o[2] = (bf16_t)v.z; o[3] = (bf16_t)v.w;
    *(bf16x4*)(dst + (size_t)idx * 4) = o;
}

extern "C" void kernel_launch(void* const* d_in, const int* in_sizes, int n_in,
                              void* d_out, int out_size, void* d_ws, size_t ws_size,
                              hipStream_t stream)
{
    (void)in_sizes; (void)n_in; (void)out_size; (void)ws_size;
    const float* X  = (const float*)d_in[0];
    const float* Wq = (const float*)d_in[1];
    const float* Wk = (const float*)d_in[2];
    const float* Wv = (const float*)d_in[3];
    float* out = (float*)d_out;

    const int Bb = 4, S = 2048, D = 1024;
    const int M = Bb * S;  // 8192

    char* ws = (char*)d_ws;
    size_t off = 0;
    auto carve = [&](size_t bytes) -> char* {
        char* p = ws + off;
        off += (bytes + 255) & ~(size_t)255;
        return p;
    };
    // Contiguity invariant: Wqb,Wkb adjacent (Wkb == Wqb + D*D): the fused
    // QK dispatch uses Wqb as a [2048][1024] B-matrix (Wq||Wk rows).
    bf16_t* Xb  = (bf16_t*)carve((size_t)M * D * 2);
    bf16_t* Wqb = (bf16_t*)carve((size_t)D * D * 2);
    bf16_t* Wkb = (bf16_t*)carve((size_t)D * D * 2);
    bf16_t* Wvb = (bf16_t*)carve((size_t)D * D * 2);
    bf16_t* Qb  = (bf16_t*)carve((size_t)M * D * 2);   // contiguous Q
    bf16_t* Kb  = (bf16_t*)carve((size_t)M * D * 2);   // contiguous K
    bf16_t* Vt  = (bf16_t*)carve((size_t)D * M * 2);   // V^T: D x M
    bf16_t* Sc  = (bf16_t*)carve((size_t)Bb * S * S * 2);
    float*  sums = (float*)carve((size_t)M * 4);

    static bool s_attr = false;
    if (!s_attr) {
        (void)hipFuncSetAttribute(
            reinterpret_cast<const void*>(&gemm8p<5, 256, bf16_t>),
            hipFuncAttributeMaxDynamicSharedMemorySize, 131072);
        (void)hipFuncSetAttribute(
            reinterpret_cast<const void*>(&gemm8p<2, 256, bf16_t>),
            hipFuncAttributeMaxDynamicSharedMemorySize, 131072);
        (void)hipFuncSetAttribute(
            reinterpret_cast<const void*>(&gemm8p<1, 128, bf16_t>),
            hipFuncAttributeMaxDynamicSharedMemorySize, 98304);
        (void)hipFuncSetAttribute(
            reinterpret_cast<const void*>(&gemm8p<3, 128, float>),
            hipFuncAttributeMaxDynamicSharedMemorySize, 98304);
        s_attr = true;
    }

    const int nX4 = M * D / 4, nW4 = D * D / 4;
    const int tot4 = nX4 + 3 * nW4;
    cvt_all<<<(tot4 + 255) / 256, 256, 0, stream>>>(
        X, Wq, Wk, Wv, Xb, Wqb, Wkb, Wvb, sums, M, nX4, nW4);

    // Fused QK: X * (Wq||Wk)^T, split-stored into contiguous Qb / Kb.
    // Grid 32x8 = 256 blocks (1 pass).
    gemm8p<5, 256, bf16_t><<<dim3(M / 256, (2 * D) / 256, 1), 512, 131072, stream>>>(
        Xb, D, 0, Wqb, D, 0, Qb, D, 0, Kb, nullptr, 0, D, 1.0f);

    // V^T direct: Vt[d][s] = sum_e Wv[d][e] X[s][e]. M=1024, N=8192.
    // Grid 4x64 = 256 blocks (1 pass); coalesced direct store, no transpose.
    gemm8p<1, 128, bf16_t><<<dim3(D / 256, M / 128, 1), 512, 98304, stream>>>(
        Wvb, D, 0, Xb, D, 0, Vt, M, 0, nullptr, nullptr, 0, D, 1.0f);

    // Sc = exp(Q K^T / 32) + row sums, contiguous inputs. 8x8x4 = 256 blocks.
    gemm8p<2, 256, bf16_t><<<dim3(S / 256, S / 256, Bb), 512, 131072, stream>>>(
        Qb, D, (size_t)S * D, Kb, D, (size_t)S * D, Sc, S, (size_t)S * S,
        nullptr, sums, S, D, 0.03125f);

    // out = (Sc V) / rowsum. M=2048/z, N=1024, K=2048. 8x8x4 = 256 blocks.
    gemm8p<3, 128, float><<<dim3(S / 256, D / 128, Bb), 512, 98304, stream>>>(
        Sc, S, (size_t)S * S, Vt, M, (size_t)S, out, D, (size_t)S * D,
        nullptr, sums, S, S, 1.0f);
}